// Round 10
// baseline (588.664 us; speedup 1.0000x reference)
//
#include <hip/hip_runtime.h>
#include <hip/hip_bf16.h>
#include <stdint.h>

typedef unsigned short u16;
typedef unsigned char  u8;
typedef int   v4i __attribute__((ext_vector_type(4)));
typedef int   v8i __attribute__((ext_vector_type(8)));
typedef float v4f __attribute__((ext_vector_type(4)));

#define N_ROWS 8192
#define C_REAL 10000
#define C_PAD  10240   /* 80 * 128 */
#define D_DIM  512
#define BM 128
#define BN 128
#define BKB 128               /* K-bytes per tile = 128 fp8 elems */
#define KTILES (D_DIM / BKB)  /* 4 */

/* LDS map (bytes): ONE 32KB tile buffer (A 16KB @0 = 128 rows x 128B swizzled
   fp8, B 16KB @16384), then f2s @32768, c2s @33280, labs @33792. Total 34304
   => 4 blocks/CU by LDS; __launch_bounds__(256,4) => 16 waves/CU from 4
   independent blocks. Byte-identical tile geometry to round 9 (0 conflicts),
   but fp8 => each tile carries K=128: staged bytes, LDS traffic and sync
   events all halve vs round 9's bf16 BK=64. */
#define SM_BOFF  16384
#define SM_F2    32768
#define SM_C2    33280
#define SM_LAB   33792
#define SM_TOTAL 34304
static_assert(4 * SM_TOTAL <= 160 * 1024, "want 4 blocks/CU");

#define BARRIER() do { asm volatile("" ::: "memory"); \
                       __builtin_amdgcn_s_barrier();  \
                       asm volatile("" ::: "memory"); } while (0)
/* MX-scaled fp8 MFMA, scale = 1.0 (E8M0 127), fmt 0 = OCP e4m3 for A and B */
#define MFMAS(d, a, b) d = __builtin_amdgcn_mfma_scale_f32_16x16x128_f8f6f4( \
    a, b, d, 0, 0, 0, 127u, 0, 127u)
#define GLL(gp, lp) __builtin_amdgcn_global_load_lds( \
    (const __attribute__((address_space(1))) void*)(gp), \
    (__attribute__((address_space(3))) void*)(lp), 16, 0, 0)

// One wave per row: L2-normalize, write fp8(e4m3) row + f32 sum-of-squares of
// the normalized row. Rows >= nreal are padding: fp8 zeros, o2 = 1e30
// (=> dis = -5e30 => exp = 0).
__global__ __launch_bounds__(256) void norm_rows_fp8_kernel(
    const float* __restrict__ x, u8* __restrict__ ob, float* __restrict__ o2,
    int nreal, int ntotal)
{
    int row  = blockIdx.x * 4 + (threadIdx.x >> 6);
    int lane = threadIdx.x & 63;
    if (row >= ntotal) return;
    uint2* orow = (uint2*)(ob + (size_t)row * D_DIM);  // 512 B/row, 8 B/lane
    if (row >= nreal) {
        uint2 z; z.x = 0u; z.y = 0u;
        orow[lane] = z;
        if (lane == 0) o2[row] = 1e30f;
        return;
    }
    const float4* xr = (const float4*)(x + (size_t)row * D_DIM);
    float4 v0 = xr[2 * lane];       // elems 8l .. 8l+3
    float4 v1 = xr[2 * lane + 1];   // elems 8l+4 .. 8l+7
    float s = v0.x*v0.x + v0.y*v0.y + v0.z*v0.z + v0.w*v0.w
            + v1.x*v1.x + v1.y*v1.y + v1.z*v1.z + v1.w*v1.w;
    #pragma unroll
    for (int m = 1; m < 64; m <<= 1) s += __shfl_xor(s, m, 64);
    float inv = 1.0f / fmaxf(sqrtf(s), 1e-12f);
    if (lane == 0) o2[row] = s * inv * inv;
    unsigned lo = __builtin_amdgcn_cvt_pk_fp8_f32(v0.x * inv, v0.y * inv, 0u, 0);
    lo = __builtin_amdgcn_cvt_pk_fp8_f32(v0.z * inv, v0.w * inv, lo, 1);
    unsigned hi = __builtin_amdgcn_cvt_pk_fp8_f32(v1.x * inv, v1.y * inv, 0u, 0);
    hi = __builtin_amdgcn_cvt_pk_fp8_f32(v1.z * inv, v1.w * inv, hi, 1);
    uint2 p; p.x = lo; p.y = hi;
    orow[lane] = p;
}

// Exact (f32) positive-class distance: one wave per row, gathered center row.
__global__ __launch_bounds__(256) void pos_exact_kernel(
    const float* __restrict__ feat, const float* __restrict__ cent,
    const int* __restrict__ labels, float* __restrict__ pose)
{
    int row  = blockIdx.x * 4 + (threadIdx.x >> 6);
    int lane = threadIdx.x & 63;
    int lab  = labels[row];
    const float4* fr = (const float4*)(feat + (size_t)row * D_DIM);
    const float4* cr = (const float4*)(cent + (size_t)lab * D_DIM);
    float sf = 0.f, sc = 0.f, sd = 0.f;
    #pragma unroll
    for (int i = 0; i < 2; ++i) {
        float4 a = fr[i * 64 + lane];
        float4 b = cr[i * 64 + lane];
        sf += a.x*a.x + a.y*a.y + a.z*a.z + a.w*a.w;
        sc += b.x*b.x + b.y*b.y + b.z*b.z + b.w*b.w;
        sd += a.x*b.x + a.y*b.y + a.z*b.z + a.w*b.w;
    }
    #pragma unroll
    for (int m = 1; m < 64; m <<= 1) {
        sf += __shfl_xor(sf, m, 64);
        sc += __shfl_xor(sc, m, 64);
        sd += __shfl_xor(sd, m, 64);
    }
    if (lane == 0) {
        float invf = 1.f / fmaxf(sqrtf(sf), 1e-12f);
        float invc = 1.f / fmaxf(sqrtf(sc), 1e-12f);
        float f2n = sf * invf * invf;
        float c2n = sc * invc * invc;
        float dtn = sd * invf * invc;
        pose[row] = -5.0f * (f2n + c2n - 2.0f * dtn);
    }
}

// 128x128 4-wave MX-fp8 GEMM (K=128/tile), SINGLE 32KB buffer, 4 blocks/CU.
// Round 9's verified loop structure unchanged: fully unrolled, zero address
// VALU (constant pointer offsets fold into offset: fields), per tile
// {lgkmcnt(0), barrier, 8 GLL, vmcnt(0), barrier, 32 ds_read_b128 + 16 MFMA}.
// Tile geometry byte-identical to round 9 (128 rows x 128B, XOR-8 swizzle,
// 0 conflicts) but fp8 doubles K per tile: staged bytes / LDS traffic /
// barriers halve, MX MFMA rate ~1.9x. B-frags streamed (1 live) to hold
// ~128 regs at 4 waves/SIMD. Grid (80,64): 80%8==0 => XCD = x%8 =>
// per-XCD B-slice + window A < 4MB L2 (round-9 measured FETCH 38MB).
__global__ __launch_bounds__(256, 4) void gemm_kernel(
    const u8* __restrict__ A, const u8* __restrict__ B,
    const float* __restrict__ f2, const float* __restrict__ c2,
    const int* __restrict__ labels,
    float* __restrict__ rowsum, float* __restrict__ posdis)
{
    extern __shared__ char sm[];
    const int rowBase = blockIdx.y * BM;
    const int colBase = blockIdx.x * BN;
    const int tid  = threadIdx.x;
    const int lane = tid & 63;
    const int w    = tid >> 6;      // 0..3
    const int wr   = w >> 1;        // 0..1 : 64-row group
    const int wc   = w & 1;         // 0..1 : 64-col group
    const int l15  = lane & 15;
    const int h4   = lane >> 4;

    // ---- staging: tile = 128 rows x 8 chunks(16B); thread covers chunk
    // c = tid + i*256: r = (tid>>3)+i*32, pc = tid&7, lc = pc ^ (r&7),
    // (r&7) invariant under +i*32. Row stride = D_DIM bytes (fp8).
    const int r0  = tid >> 3;                       // 0..31
    const int lc0 = (tid & 7) ^ (r0 & 7);
    const size_t gOff = (size_t)r0 * D_DIM + lc0 * 16;  // bytes
    const u8* aP = A + (size_t)rowBase * D_DIM + gOff;  // +16384 B per i
    const u8* bP = B + (size_t)colBase * D_DIM + gOff;
    char* lA = sm + tid * 16;                           // +4096 per i
    char* lB = sm + SM_BOFF + tid * 16;

    // KOFS (bytes) is a compile-time constant per unroll.
    #define STAGE8(KOFS) do { \
        GLL(aP + (KOFS),         lA);         \
        GLL(aP + (KOFS) + 16384, lA + 4096);  \
        GLL(aP + (KOFS) + 32768, lA + 8192);  \
        GLL(aP + (KOFS) + 49152, lA + 12288); \
        GLL(bP + (KOFS),         lB);         \
        GLL(bP + (KOFS) + 16384, lB + 4096);  \
        GLL(bP + (KOFS) + 32768, lB + 8192);  \
        GLL(bP + (KOFS) + 49152, lB + 12288); \
    } while (0)

    // ---- fragment read bases: lane (row=l15, h4) needs logical chunks
    // 2h4, 2h4+1 (32 contiguous K-bytes); physical chunk = logical ^ (l15&7)
    // => lo at base, hi at base^16 (adjacent chunk bit).
    const int sw  = (((h4 << 1)) ^ (l15 & 7)) << 4;
    const int aB  = wr * 8192 + l15 * 128 + sw;
    const int bB  = SM_BOFF + wc * 8192 + l15 * 128 + sw;

    // ---- prologue: epilogue tables + tile 0; full drain once ----
    if (tid < 128) {
        ((float*)(sm + SM_F2))[tid] = f2[rowBase + tid];
        ((int*)(sm + SM_LAB))[tid]  = labels[rowBase + tid];
    } else {
        ((float*)(sm + SM_C2))[tid - 128] = c2[colBase + (tid - 128)];
    }
    STAGE8(0);
    __syncthreads();

    v4f acc[4][4];
    #pragma unroll
    for (int m = 0; m < 4; ++m)
        #pragma unroll
        for (int n = 0; n < 4; ++n) acc[m][n] = (v4f){0.f, 0.f, 0.f, 0.f};

    auto rd32 = [&](int off) -> v8i {   // 32B fragment = 2 x b128
        v4i lo = *(const v4i*)(sm + off);
        v4i hi = *(const v4i*)(sm + (off ^ 16));
        return __builtin_shufflevector(lo, hi, 0, 1, 2, 3, 4, 5, 6, 7);
    };

    auto compute = [&]() {
        v8i a[4];
        #pragma unroll
        for (int m = 0; m < 4; ++m) a[m] = rd32(aB + m * 2048);
        #pragma unroll
        for (int n = 0; n < 4; ++n) {
            v8i b = rd32(bB + n * 2048);
            __builtin_amdgcn_s_setprio(1);
            #pragma unroll
            for (int m = 0; m < 4; ++m)
                MFMAS(acc[m][n], a[m], b);
            __builtin_amdgcn_s_setprio(0);
        }
    };

    // 4 K-tiles; single buffer reused — all tile-k LDS reads complete before
    // the pre-stage barrier (lgkmcnt(0) makes it airtight).
    #define NEXT_TILE(KOFS) do { \
        asm volatile("s_waitcnt lgkmcnt(0)" ::: "memory"); \
        BARRIER(); \
        STAGE8(KOFS); \
        asm volatile("s_waitcnt vmcnt(0)" ::: "memory"); \
        BARRIER(); \
        compute(); \
    } while (0)

    compute();
    NEXT_TILE(128);
    NEXT_TILE(256);
    NEXT_TILE(384);
    #undef NEXT_TILE
    #undef STAGE8

    // Epilogue: dis = -5*(f2 + c2 - 2*dot); exp; per-row sums; label capture.
    float* rs = rowsum + (size_t)(blockIdx.x & 7) * N_ROWS;  // per-XCD slice
    const float* f2s  = (const float*)(sm + SM_F2);
    const float* c2s  = (const float*)(sm + SM_C2);
    const int*   labs = (const int*)(sm + SM_LAB);
    #pragma unroll
    for (int m = 0; m < 4; ++m) {
        float s[4] = {0.f, 0.f, 0.f, 0.f};
        const int lr0 = wr * 64 + m * 16 + h4 * 4;
        #pragma unroll
        for (int n = 0; n < 4; ++n) {
            const int lcol = wc * 64 + n * 16 + l15;
            const int gcol = colBase + lcol;
            const float cc = c2s[lcol];
            #pragma unroll
            for (int j = 0; j < 4; ++j) {
                const int lr = lr0 + j;
                float dis = -5.0f * (f2s[lr] + cc - 2.0f * acc[m][n][j]);
                float e = __expf(dis);
                s[j] += e;
                if (labs[lr] == gcol) posdis[rowBase + lr] = dis;
            }
        }
        #pragma unroll
        for (int msk = 1; msk < 16; msk <<= 1) {
            #pragma unroll
            for (int j = 0; j < 4; ++j) s[j] += __shfl_xor(s[j], msk, 64);
        }
        if (l15 == 0) {
            #pragma unroll
            for (int j = 0; j < 4; ++j)
                atomicAdd(&rs[rowBase + lr0 + j], s[j]);
        }
    }
}

// Final scalar reduction: loss and unbiased variance (f64 accumulation).
__global__ __launch_bounds__(256) void finalize_kernel(
    const float* __restrict__ posdis, const float* __restrict__ pose,
    const float* __restrict__ rowsum, const int* __restrict__ labels,
    const float* __restrict__ bias, float* __restrict__ out)
{
    int t = threadIdx.x;
    double sl = 0.0, sp = 0.0, sp2 = 0.0;
    for (int r = t; r < N_ROWS; r += 256) {
        float rsum = 0.f;
        #pragma unroll
        for (int x = 0; x < 8; ++x) rsum += rowsum[x * N_ROWS + r];
        float pd = posdis[r];                 // fp8-path label term (matches rowsum)
        float p  = pose[r] + bias[labels[r]]; // exact-path pos_metric
        float num = __expf(p);
        float den = rsum - __expf(pd) + num;
        sl  += (double)(logf(den) - p);
        sp  += (double)p;
        sp2 += (double)p * (double)p;
    }
    #pragma unroll
    for (int m = 1; m < 64; m <<= 1) {
        sl  += __shfl_xor(sl,  m, 64);
        sp  += __shfl_xor(sp,  m, 64);
        sp2 += __shfl_xor(sp2, m, 64);
    }
    __shared__ double sh[3][4];
    int w = t >> 6, lane = t & 63;
    if (lane == 0) { sh[0][w] = sl; sh[1][w] = sp; sh[2][w] = sp2; }
    __syncthreads();
    if (t == 0) {
        sl  = sh[0][0] + sh[0][1] + sh[0][2] + sh[0][3];
        sp  = sh[1][0] + sh[1][1] + sh[1][2] + sh[1][3];
        sp2 = sh[2][0] + sh[2][1] + sh[2][2] + sh[2][3];
        const double N = (double)N_ROWS;
        double mean = sp / N;
        double var  = (sp2 - N * mean * mean) / (N - 1.0);
        double loss = sl / N + var;
        out[0] = (float)loss;
        out[1] = (float)var;
    }
}

extern "C" void kernel_launch(void* const* d_in, const int* in_sizes, int n_in,
                              void* d_out, int out_size, void* d_ws, size_t ws_size,
                              hipStream_t stream) {
    const float* features = (const float*)d_in[0];
    const int*   labels   = (const int*)d_in[1];
    const float* centers  = (const float*)d_in[2];
    const float* bias     = (const float*)d_in[3];
    float* out = (float*)d_out;
    char* ws = (char*)d_ws;

    // Workspace layout (16B aligned), ~9.8 MB total.
    u8*    fb     = (u8*)(ws);                 // 8192*512  = 4194304
    u8*    cb     = (u8*)(ws + 4194304);       // 10240*512 = 5242880
    float* f2     = (float*)(ws + 9437184);    // 8192*4
    float* c2     = (float*)(ws + 9469952);    // 10240*4
    float* rowsum = (float*)(ws + 9510912);    // 8*8192*4 = 262144
    float* posdis = (float*)(ws + 9773056);    // 8192*4
    float* pose   = (float*)(ws + 9805824);    // 8192*4

    hipMemsetAsync(rowsum, 0, 8 * N_ROWS * sizeof(float), stream);

    hipLaunchKernelGGL(norm_rows_fp8_kernel, dim3(N_ROWS / 4), dim3(256), 0, stream,
                       features, fb, f2, N_ROWS, N_ROWS);
    hipLaunchKernelGGL(norm_rows_fp8_kernel, dim3(C_PAD / 4), dim3(256), 0, stream,
                       centers, cb, c2, C_REAL, C_PAD);
    hipLaunchKernelGGL(pos_exact_kernel, dim3(N_ROWS / 4), dim3(256), 0, stream,
                       features, centers, labels, pose);

    hipFuncSetAttribute(reinterpret_cast<const void*>(gemm_kernel),
                        hipFuncAttributeMaxDynamicSharedMemorySize, SM_TOTAL);
    hipLaunchKernelGGL(gemm_kernel, dim3(C_PAD / BN, N_ROWS / BM), dim3(256), SM_TOTAL, stream,
                       fb, cb, f2, c2, labels, rowsum, posdis);

    hipLaunchKernelGGL(finalize_kernel, dim3(1), dim3(256), 0, stream,
                       posdis, pose, rowsum, labels, bias, out);
}

// Round 11
// 162.514 us; speedup vs baseline: 3.6222x; 3.6222x over previous
//
#include <hip/hip_runtime.h>
#include <hip/hip_bf16.h>
#include <stdint.h>

typedef unsigned short u16;
typedef __bf16 v8bf __attribute__((ext_vector_type(8)));
typedef float  v4f  __attribute__((ext_vector_type(4)));

#define N_ROWS 8192
#define C_REAL 10000
#define C_PAD  10240   /* 80 * 128 */
#define D_DIM  512
#define BM 128
#define BN 128
#define BK 64
#define KTILES (D_DIM / BK)   /* 8 */

/* LDS map (bytes): ONE 32KB tile buffer (A 16KB @0 = 128 rows x 128B swizzled,
   B 16KB @16384), then f2s @32768, c2s @33280, labs @33792. Total 34304
   => 4 blocks/CU by LDS; __launch_bounds__(256,4) => 16 waves/CU from 4
   independent blocks (cross-block overlap hides stage drains, m114). */
#define SM_BOFF  16384
#define SM_F2    32768
#define SM_C2    33280
#define SM_LAB   33792
#define SM_TOTAL 34304
static_assert(4 * SM_TOTAL <= 160 * 1024, "want 4 blocks/CU");

#define NPART 32   /* finalize stage-1 blocks */

#define BARRIER() do { asm volatile("" ::: "memory"); \
                       __builtin_amdgcn_s_barrier();  \
                       asm volatile("" ::: "memory"); } while (0)
#define MFMA(d, a, b) d = __builtin_amdgcn_mfma_f32_16x16x32_bf16(a, b, d, 0, 0, 0)
#define GLL(gp, lp) __builtin_amdgcn_global_load_lds( \
    (const __attribute__((address_space(1))) void*)(gp), \
    (__attribute__((address_space(3))) void*)(lp), 16, 0, 0)

__device__ __forceinline__ unsigned pack2bf(float a, float b) {
    unsigned short ua = __builtin_bit_cast(unsigned short, (__bf16)a);
    unsigned short ub = __builtin_bit_cast(unsigned short, (__bf16)b);
    return (unsigned)ua | ((unsigned)ub << 16);
}

// L2-normalize one row (one wave): bf16 row out + f32 sum-of-squares of the
// normalized row. Padding rows: bf16 zeros, o2 = 1e30 (exp(-5e30) = 0).
__device__ __forceinline__ void norm_row(
    const float* __restrict__ x, u16* __restrict__ ob, float* __restrict__ o2,
    int row, int nreal, int lane)
{
    uint2* orow = (uint2*)(ob + (size_t)row * D_DIM);
    if (row >= nreal) {
        uint2 z; z.x = 0u; z.y = 0u;
        orow[lane] = z; orow[64 + lane] = z;
        if (lane == 0) o2[row] = 1e30f;
        return;
    }
    const float4* xr = (const float4*)(x + (size_t)row * D_DIM);
    float4 v0 = xr[lane];
    float4 v1 = xr[64 + lane];
    float s = v0.x*v0.x + v0.y*v0.y + v0.z*v0.z + v0.w*v0.w
            + v1.x*v1.x + v1.y*v1.y + v1.z*v1.z + v1.w*v1.w;
    #pragma unroll
    for (int m = 1; m < 64; m <<= 1) s += __shfl_xor(s, m, 64);
    float inv = 1.0f / fmaxf(sqrtf(s), 1e-12f);
    if (lane == 0) o2[row] = s * inv * inv;
    uint2 p0, p1;
    p0.x = pack2bf(v0.x * inv, v0.y * inv);
    p0.y = pack2bf(v0.z * inv, v0.w * inv);
    p1.x = pack2bf(v1.x * inv, v1.y * inv);
    p1.y = pack2bf(v1.z * inv, v1.w * inv);
    orow[lane]      = p0;
    orow[64 + lane] = p1;
}

// Exact (f32) positive-class distance for one row (one wave).
__device__ __forceinline__ void pos_row(
    const float* __restrict__ feat, const float* __restrict__ cent,
    const int* __restrict__ labels, float* __restrict__ pose,
    int row, int lane)
{
    int lab = labels[row];
    const float4* fr = (const float4*)(feat + (size_t)row * D_DIM);
    const float4* cr = (const float4*)(cent + (size_t)lab * D_DIM);
    float sf = 0.f, sc = 0.f, sd = 0.f;
    #pragma unroll
    for (int i = 0; i < 2; ++i) {
        float4 a = fr[i * 64 + lane];
        float4 b = cr[i * 64 + lane];
        sf += a.x*a.x + a.y*a.y + a.z*a.z + a.w*a.w;
        sc += b.x*b.x + b.y*b.y + b.z*b.z + b.w*b.w;
        sd += a.x*b.x + a.y*b.y + a.z*b.z + a.w*b.w;
    }
    #pragma unroll
    for (int m = 1; m < 64; m <<= 1) {
        sf += __shfl_xor(sf, m, 64);
        sc += __shfl_xor(sc, m, 64);
        sd += __shfl_xor(sd, m, 64);
    }
    if (lane == 0) {
        float invf = 1.f / fmaxf(sqrtf(sf), 1e-12f);
        float invc = 1.f / fmaxf(sqrtf(sc), 1e-12f);
        pose[row] = -5.0f * (sf * invf * invf + sc * invc * invc
                             - 2.0f * sd * invf * invc);
    }
}

// Fused prep: one launch covers norm(features), norm(centers+pad), pos_exact.
// Segments by blockIdx so the three independent memory-bound workloads
// overlap instead of running as 3 serialized launches.
//   blocks [0, 2048)        : features rows 4b..4b+3
//   blocks [2048, 4608)     : centers rows 4(b-2048)..
//   blocks [4608, 6656)     : pos rows 4(b-4608)..
__global__ __launch_bounds__(256) void prep_kernel(
    const float* __restrict__ features, const float* __restrict__ centers,
    const int* __restrict__ labels,
    u16* __restrict__ fb, u16* __restrict__ cb,
    float* __restrict__ f2, float* __restrict__ c2, float* __restrict__ pose)
{
    int b = blockIdx.x;
    int sub = threadIdx.x >> 6;
    int lane = threadIdx.x & 63;
    if (b < 2048) {
        norm_row(features, fb, f2, b * 4 + sub, N_ROWS, lane);
    } else if (b < 4608) {
        norm_row(centers, cb, c2, (b - 2048) * 4 + sub, C_REAL, lane);
    } else {
        pos_row(features, centers, labels, pose, (b - 4608) * 4 + sub, lane);
    }
}

// 128x128x(BK=64) 4-wave MFMA GEMM, SINGLE 32KB buffer, 4 blocks/CU.
// (round 9's verified kernel, unchanged — 145us, MfmaUtil 24%, 0 conflicts)
__global__ __launch_bounds__(256, 4) void gemm_kernel(
    const u16* __restrict__ A, const u16* __restrict__ B,
    const float* __restrict__ f2, const float* __restrict__ c2,
    const int* __restrict__ labels,
    float* __restrict__ rowsum, float* __restrict__ posdis)
{
    extern __shared__ char sm[];
    const int rowBase = blockIdx.y * BM;
    const int colBase = blockIdx.x * BN;
    const int tid  = threadIdx.x;
    const int lane = tid & 63;
    const int w    = tid >> 6;      // 0..3
    const int wr   = w >> 1;        // 0..1 : 64-row group
    const int wc   = w & 1;         // 0..1 : 64-col group
    const int l15  = lane & 15;
    const int h4   = lane >> 4;

    const int r0  = tid >> 3;                       // 0..31
    const int lc0 = (tid & 7) ^ (r0 & 7);
    const size_t gOff = (size_t)r0 * D_DIM + lc0 * 8;   // elements
    const u16* aP = A + (size_t)rowBase * D_DIM + gOff; // +16384 elems per i
    const u16* bP = B + (size_t)colBase * D_DIM + gOff;
    char* lA = sm + tid * 16;                           // +4096 per i
    char* lB = sm + SM_BOFF + tid * 16;

    #define STAGE8(KOFS) do { \
        GLL(aP + (KOFS),         lA);         \
        GLL(aP + (KOFS) + 16384, lA + 4096);  \
        GLL(aP + (KOFS) + 32768, lA + 8192);  \
        GLL(aP + (KOFS) + 49152, lA + 12288); \
        GLL(bP + (KOFS),         lB);         \
        GLL(bP + (KOFS) + 16384, lB + 4096);  \
        GLL(bP + (KOFS) + 32768, lB + 8192);  \
        GLL(bP + (KOFS) + 49152, lB + 12288); \
    } while (0)

    const int s0 = ((h4)     ^ (l15 & 7)) << 4;
    const int s1 = ((4 + h4) ^ (l15 & 7)) << 4;
    const int aB0 = wr * 8192 + l15 * 128 + s0;
    const int aB1 = wr * 8192 + l15 * 128 + s1;
    const int bB0 = SM_BOFF + wc * 8192 + l15 * 128 + s0;
    const int bB1 = SM_BOFF + wc * 8192 + l15 * 128 + s1;

    if (tid < 128) {
        ((float*)(sm + SM_F2))[tid] = f2[rowBase + tid];
        ((int*)(sm + SM_LAB))[tid]  = labels[rowBase + tid];
    } else {
        ((float*)(sm + SM_C2))[tid - 128] = c2[colBase + (tid - 128)];
    }
    STAGE8(0);
    __syncthreads();

    v4f acc[4][4];
    #pragma unroll
    for (int m = 0; m < 4; ++m)
        #pragma unroll
        for (int n = 0; n < 4; ++n) acc[m][n] = (v4f){0.f, 0.f, 0.f, 0.f};

    auto compute = [&]() {
        v8bf a[4], b[4];
        #pragma unroll
        for (int m = 0; m < 4; ++m) a[m] = *(const v8bf*)(sm + aB0 + m * 2048);
        #pragma unroll
        for (int n = 0; n < 4; ++n) b[n] = *(const v8bf*)(sm + bB0 + n * 2048);
        __builtin_amdgcn_s_setprio(1);
        #pragma unroll
        for (int m = 0; m < 4; ++m)
            #pragma unroll
            for (int n = 0; n < 4; ++n)
                MFMA(acc[m][n], a[m], b[n]);
        __builtin_amdgcn_s_setprio(0);
        #pragma unroll
        for (int m = 0; m < 4; ++m) a[m] = *(const v8bf*)(sm + aB1 + m * 2048);
        #pragma unroll
        for (int n = 0; n < 4; ++n) b[n] = *(const v8bf*)(sm + bB1 + n * 2048);
        __builtin_amdgcn_s_setprio(1);
        #pragma unroll
        for (int m = 0; m < 4; ++m)
            #pragma unroll
            for (int n = 0; n < 4; ++n)
                MFMA(acc[m][n], a[m], b[n]);
        __builtin_amdgcn_s_setprio(0);
    };

    #define NEXT_TILE(KOFS) do { \
        asm volatile("s_waitcnt lgkmcnt(0)" ::: "memory"); \
        BARRIER(); \
        STAGE8(KOFS); \
        asm volatile("s_waitcnt vmcnt(0)" ::: "memory"); \
        BARRIER(); \
        compute(); \
    } while (0)

    compute();
    NEXT_TILE(64);
    NEXT_TILE(128);
    NEXT_TILE(192);
    NEXT_TILE(256);
    NEXT_TILE(320);
    NEXT_TILE(384);
    NEXT_TILE(448);
    #undef NEXT_TILE
    #undef STAGE8

    // Epilogue: dis = -5*(f2 + c2 - 2*dot); exp; per-row sums; label capture.
    float* rs = rowsum + (size_t)(blockIdx.x & 7) * N_ROWS;  // per-XCD slice
    const float* f2s  = (const float*)(sm + SM_F2);
    const float* c2s  = (const float*)(sm + SM_C2);
    const int*   labs = (const int*)(sm + SM_LAB);
    #pragma unroll
    for (int m = 0; m < 4; ++m) {
        float s[4] = {0.f, 0.f, 0.f, 0.f};
        const int lr0 = wr * 64 + m * 16 + h4 * 4;
        #pragma unroll
        for (int n = 0; n < 4; ++n) {
            const int lcol = wc * 64 + n * 16 + l15;
            const int gcol = colBase + lcol;
            const float cc = c2s[lcol];
            #pragma unroll
            for (int j = 0; j < 4; ++j) {
                const int lr = lr0 + j;
                float dis = -5.0f * (f2s[lr] + cc - 2.0f * acc[m][n][j]);
                float e = __expf(dis);
                s[j] += e;
                if (labs[lr] == gcol) posdis[rowBase + lr] = dis;
            }
        }
        #pragma unroll
        for (int msk = 1; msk < 16; msk <<= 1) {
            #pragma unroll
            for (int j = 0; j < 4; ++j) s[j] += __shfl_xor(s[j], msk, 64);
        }
        if (l15 == 0) {
            #pragma unroll
            for (int j = 0; j < 4; ++j)
                atomicAdd(&rs[rowBase + lr0 + j], s[j]);
        }
    }
}

// Finalize stage 1: NPART blocks each reduce 256 rows -> f64 partial triple.
// No atomics (deterministic); stage 2 combines in fixed order.
__global__ __launch_bounds__(256) void finalize_part_kernel(
    const float* __restrict__ posdis, const float* __restrict__ pose,
    const float* __restrict__ rowsum, const int* __restrict__ labels,
    const float* __restrict__ bias, double* __restrict__ partials)
{
    int t = threadIdx.x;
    int r = blockIdx.x * (N_ROWS / NPART) + t;   // 256 rows/block, 1 per thread
    float rsum = 0.f;
    #pragma unroll
    for (int x = 0; x < 8; ++x) rsum += rowsum[x * N_ROWS + r];
    float pd = posdis[r];                 // bf16-path label term (matches rowsum)
    float p  = pose[r] + bias[labels[r]]; // exact-path pos_metric
    float num = __expf(p);
    float den = rsum - __expf(pd) + num;
    double sl  = (double)(logf(den) - p);
    double sp  = (double)p;
    double sp2 = (double)p * (double)p;
    #pragma unroll
    for (int m = 1; m < 64; m <<= 1) {
        sl  += __shfl_xor(sl,  m, 64);
        sp  += __shfl_xor(sp,  m, 64);
        sp2 += __shfl_xor(sp2, m, 64);
    }
    __shared__ double sh[3][4];
    int w = t >> 6, lane = t & 63;
    if (lane == 0) { sh[0][w] = sl; sh[1][w] = sp; sh[2][w] = sp2; }
    __syncthreads();
    if (t == 0) {
        partials[blockIdx.x * 3 + 0] = sh[0][0] + sh[0][1] + sh[0][2] + sh[0][3];
        partials[blockIdx.x * 3 + 1] = sh[1][0] + sh[1][1] + sh[1][2] + sh[1][3];
        partials[blockIdx.x * 3 + 2] = sh[2][0] + sh[2][1] + sh[2][2] + sh[2][3];
    }
}

// Finalize stage 2: one wave combines NPART partials (fixed shuffle-tree
// order => deterministic) and writes loss/variance.
__global__ __launch_bounds__(64) void finalize_comb_kernel(
    const double* __restrict__ partials, float* __restrict__ out)
{
    int t = threadIdx.x;
    double sl = 0.0, sp = 0.0, sp2 = 0.0;
    if (t < NPART) {
        sl  = partials[t * 3 + 0];
        sp  = partials[t * 3 + 1];
        sp2 = partials[t * 3 + 2];
    }
    #pragma unroll
    for (int m = 1; m < 64; m <<= 1) {
        sl  += __shfl_xor(sl,  m, 64);
        sp  += __shfl_xor(sp,  m, 64);
        sp2 += __shfl_xor(sp2, m, 64);
    }
    if (t == 0) {
        const double N = (double)N_ROWS;
        double mean = sp / N;
        double var  = (sp2 - N * mean * mean) / (N - 1.0);
        out[0] = (float)(sl / N + var);
        out[1] = (float)var;
    }
}

extern "C" void kernel_launch(void* const* d_in, const int* in_sizes, int n_in,
                              void* d_out, int out_size, void* d_ws, size_t ws_size,
                              hipStream_t stream) {
    const float* features = (const float*)d_in[0];
    const int*   labels   = (const int*)d_in[1];
    const float* centers  = (const float*)d_in[2];
    const float* bias     = (const float*)d_in[3];
    float* out = (float*)d_out;
    char* ws = (char*)d_ws;

    // Workspace layout (16B aligned), ~19.3 MB total.
    u16*    fb     = (u16*)(ws);                 // 8192*512*2  = 8388608
    u16*    cb     = (u16*)(ws + 8388608);       // 10240*512*2 = 10485760
    float*  f2     = (float*)(ws + 18874368);    // 8192*4
    float*  c2     = (float*)(ws + 18907136);    // 10240*4
    float*  rowsum = (float*)(ws + 18948096);    // 8*8192*4 = 262144
    float*  posdis = (float*)(ws + 19210240);    // 8192*4
    float*  pose   = (float*)(ws + 19243008);    // 8192*4
    double* parts  = (double*)(ws + 19275776);   // 32*3*8 = 768

    hipMemsetAsync(rowsum, 0, 8 * N_ROWS * sizeof(float), stream);

    hipLaunchKernelGGL(prep_kernel, dim3(6656), dim3(256), 0, stream,
                       features, centers, labels, fb, cb, f2, c2, pose);

    hipFuncSetAttribute(reinterpret_cast<const void*>(gemm_kernel),
                        hipFuncAttributeMaxDynamicSharedMemorySize, SM_TOTAL);
    hipLaunchKernelGGL(gemm_kernel, dim3(C_PAD / BN, N_ROWS / BM), dim3(256), SM_TOTAL, stream,
                       fb, cb, f2, c2, labels, rowsum, posdis);

    hipLaunchKernelGGL(finalize_part_kernel, dim3(NPART), dim3(256), 0, stream,
                       posdis, pose, rowsum, labels, bias, parts);
    hipLaunchKernelGGL(finalize_comb_kernel, dim3(1), dim3(64), 0, stream,
                       parts, out);
}